// Round 9
// baseline (389.314 us; speedup 1.0000x reference)
//
#include <hip/hip_runtime.h>

// R9 = R8 + INTERNAL REPETITION for instrumentation: k1 body x32, k2 body x8.
// Both are idempotent (rewrite identical values), so correctness holds.
// Purpose: push both kernels above the ~75us harness fills so they appear in
// rocprof top-5 WITH counters. Per-rep duration = dispatch dur / reps.

#define C_ 128
#define K_ 64
#define H_ 40
#define W_ 30
#define N_ 4
#define HW_ 1200          // H_*W_
#define P_ 5
#define OH_ 36            // H_+1-P_
#define OW_ 26            // W_+1-P_
#define OHW_ 936

#define K1_REPS 32
#define K2_REPS 8

template<int CTRL>
__device__ __forceinline__ float dpp0f(float v) {
  return __int_as_float(__builtin_amdgcn_update_dpp(
      0, __float_as_int(v), CTRL, 0xF, 0xF, true));
}
__device__ __forceinline__ float swz_x16(float v) {
  return __int_as_float(__builtin_amdgcn_ds_swizzle(__float_as_int(v), 0x401F));
}

__global__ __launch_bounds__(256) void k1_fused(
    const float* __restrict__ x, const float* __restrict__ cw,
    float* __restrict__ xn, float* __restrict__ sa)
{
  __shared__ float xs[8][132];
  __shared__ float ls[8][68];
  __shared__ float red[8][36];
  __shared__ float rnorm_s[8];
  __shared__ float smax_s[8];
  __shared__ float rsum_s[8];

  const int tid = threadIdx.x;
  const int bid = blockIdx.x;
  const int n   = bid / 150;
  const int rem = (bid - n*150) * 8;
  const float* __restrict__ xb = x + (size_t)n*C_*HW_ + rem;

  const int pix = tid & 7;
  const int q   = tid >> 3;

  #pragma nounroll
  for (int rep = 0; rep < K1_REPS; ++rep) {
    asm volatile("" ::: "memory");

    // ---- stage x -> xs[pix][c]
    {
      const int c  = tid >> 1;
      const int p0 = (tid & 1) << 2;
      const float4 v = *(const float4*)(xb + (size_t)c*HW_ + p0);
      xs[p0+0][c] = v.x; xs[p0+1][c] = v.y;
      xs[p0+2][c] = v.z; xs[p0+3][c] = v.w;
    }
    __syncthreads();

    // ---- norm partials
    {
      const float4 v = *(const float4*)&xs[pix][q*4];
      red[pix][q] = (v.x*v.x + v.y*v.y) + (v.z*v.z + v.w*v.w);
    }
    __syncthreads();
    if (tid < 64) {
      const int p = tid >> 3, j = tid & 7;
      float s = ((red[p][j] + red[p][j+8]) + (red[p][j+16] + red[p][j+24]));
      s += __shfl_xor(s, 1, 64); s += __shfl_xor(s, 2, 64); s += __shfl_xor(s, 4, 64);
      if (j == 0) rnorm_s[p] = 1.f / fmaxf(sqrtf(s), 1e-12f);
    }
    __syncthreads();

    // ---- conv
    {
      const float* __restrict__ w0 = cw + (q*2)*C_;
      const float* __restrict__ w1 = w0 + C_;
      float a0 = 0.f, a1 = 0.f;
      #pragma unroll 8
      for (int c0 = 0; c0 < C_; c0 += 4) {
        const float4 xv = *(const float4*)&xs[pix][c0];
        const float4 wa = *(const float4*)(w0 + c0);
        const float4 wb = *(const float4*)(w1 + c0);
        a0 = fmaf(wa.x, xv.x, a0); a0 = fmaf(wa.y, xv.y, a0);
        a0 = fmaf(wa.z, xv.z, a0); a0 = fmaf(wa.w, xv.w, a0);
        a1 = fmaf(wb.x, xv.x, a1); a1 = fmaf(wb.y, xv.y, a1);
        a1 = fmaf(wb.z, xv.z, a1); a1 = fmaf(wb.w, xv.w, a1);
      }
      const float rn = rnorm_s[pix];
      float2 lv; lv.x = a0 * rn; lv.y = a1 * rn;
      *(float2*)&ls[pix][q*2] = lv;
    }

    // ---- write xn
    {
      const int c  = tid >> 1;
      const int p0 = (tid & 1) << 2;
      float4 o;
      o.x = xs[p0+0][c] * rnorm_s[p0+0];
      o.y = xs[p0+1][c] * rnorm_s[p0+1];
      o.z = xs[p0+2][c] * rnorm_s[p0+2];
      o.w = xs[p0+3][c] * rnorm_s[p0+3];
      *(float4*)(xn + ((size_t)n*C_ + c)*HW_ + rem + p0) = o;
    }
    __syncthreads();

    // ---- softmax max
    if (tid < 64) {
      const int p = tid >> 3, j = tid & 7;
      const float4 v0 = *(const float4*)&ls[p][j*8];
      const float4 v1 = *(const float4*)&ls[p][j*8 + 4];
      float m = fmaxf(fmaxf(fmaxf(v0.x, v0.y), fmaxf(v0.z, v0.w)),
                      fmaxf(fmaxf(v1.x, v1.y), fmaxf(v1.z, v1.w)));
      m = fmaxf(m, __shfl_xor(m, 1, 64));
      m = fmaxf(m, __shfl_xor(m, 2, 64));
      m = fmaxf(m, __shfl_xor(m, 4, 64));
      if (j == 0) smax_s[p] = m;
    }
    __syncthreads();

    // ---- exp + partial sums
    {
      const float m = smax_s[pix];
      const float2 lv = *(const float2*)&ls[pix][q*2];
      const float e0 = expf(lv.x - m);
      const float e1 = expf(lv.y - m);
      float2 ev; ev.x = e0; ev.y = e1;
      *(float2*)&ls[pix][q*2] = ev;
      red[pix][q] = e0 + e1;
    }
    __syncthreads();
    if (tid < 64) {
      const int p = tid >> 3, j = tid & 7;
      float s = ((red[p][j] + red[p][j+8]) + (red[p][j+16] + red[p][j+24]));
      s += __shfl_xor(s, 1, 64); s += __shfl_xor(s, 2, 64); s += __shfl_xor(s, 4, 64);
      if (j == 0) rsum_s[p] = 1.f / s;
    }
    __syncthreads();

    // ---- write sa
    {
      const int k  = tid >> 2;
      const int ph = (tid & 3) << 1;
      float2 o;
      o.x = ls[ph + 0][k] * rsum_s[ph + 0];
      o.y = ls[ph + 1][k] * rsum_s[ph + 1];
      *(float2*)(sa + ((size_t)n*K_ + k)*HW_ + rem + ph) = o;
    }
    __syncthreads();
  }
}

__global__ __launch_bounds__(256, 6) void k2_box(
    const float* __restrict__ xn, const float* __restrict__ sa,
    const float* __restrict__ cent, float* __restrict__ out)
{
  const int tid = threadIdx.x;
  const int w   = tid & 31;
  const int wc  = (w < W_) ? w : (W_ - 1);
  const int c   = (blockIdx.x << 3) + (tid >> 5);
  const int k   = blockIdx.y;
  const int nh  = blockIdx.z;
  const int n   = nh >> 1;
  const int r0  = (nh & 1) * 18;

  const float cv = cent[k*C_ + c];
  const float* __restrict__ xp = xn + (size_t)(n*C_ + c)*HW_ + (size_t)r0*W_ + wc;
  const float* __restrict__ sp = sa + (size_t)(n*K_ + k)*HW_ + (size_t)r0*W_ + wc;
  float* __restrict__ op = out + (size_t)((n*K_ + k)*C_ + c)*OHW_
                               + (size_t)r0*OW_ + w;

  #pragma nounroll
  for (int rep = 0; rep < K2_REPS; ++rep) {
    asm volatile("" ::: "memory");

    float q[22];
    #pragma unroll
    for (int h = 0; h < 22; ++h) {
      q[h] = (xp[h*W_] - cv) * sp[h*W_];
    }

    float vq = q[0] + q[1] + q[2] + q[3] + q[4];

    #pragma unroll
    for (int i = 0; i < 18; ++i) {
      const float sw = swz_x16(vq);
      float hs = vq;
      hs += dpp0f<0x101>(vq) + dpp0f<0x11F>(sw);
      hs += dpp0f<0x102>(vq) + dpp0f<0x11E>(sw);
      hs += dpp0f<0x103>(vq) + dpp0f<0x11D>(sw);
      hs += dpp0f<0x104>(vq) + dpp0f<0x11C>(sw);
      if (w < OW_) op[i*OW_] = hs * (1.f / (P_*P_));
      if (i < 17) vq += q[i + P_] - q[i];
    }
  }
}

extern "C" void kernel_launch(void* const* d_in, const int* in_sizes, int n_in,
                              void* d_out, int out_size, void* d_ws, size_t ws_size,
                              hipStream_t stream) {
  const float* x  = (const float*)d_in[0];
  const float* cw = (const float*)d_in[1];  // [K,C]
  const float* ce = (const float*)d_in[2];  // [K,C]

  float* xn = (float*)d_ws;
  float* sa = xn + (size_t)N_*C_*HW_;
  float* out = (float*)d_out;

  k1_fused<<<dim3(600), dim3(256), 0, stream>>>(x, cw, xn, sa);
  k2_box  <<<dim3(C_/8, K_, N_*2), dim3(256), 0, stream>>>(xn, sa, ce, out);
}

// Round 10
// 42.019 us; speedup vs baseline: 9.2653x; 9.2653x over previous
//
#include <hip/hip_runtime.h>

#define C_ 128
#define K_ 64
#define H_ 40
#define W_ 30
#define N_ 4
#define HW_ 1200          // H_*W_
#define P_ 5
#define OH_ 36            // H_+1-P_
#define OW_ 26            // W_+1-P_
#define OHW_ 936

template<int CTRL>
__device__ __forceinline__ float dpp0f(float v) {
  return __int_as_float(__builtin_amdgcn_update_dpp(
      0, __float_as_int(v), CTRL, 0xF, 0xF, true));
}
__device__ __forceinline__ float swz_x16(float v) {
  return __int_as_float(__builtin_amdgcn_ds_swizzle(__float_as_int(v), 0x401F));
}

// ---------------------------------------------------------------------------
// K1: R8 verbatim (warm 7.4us; VALUBusy 24%, latency-bound, good enough).
// ---------------------------------------------------------------------------
__global__ __launch_bounds__(256) void k1_fused(
    const float* __restrict__ x, const float* __restrict__ cw,
    float* __restrict__ xn, float* __restrict__ sa)
{
  __shared__ float xs[8][132];
  __shared__ float ls[8][68];
  __shared__ float red[8][36];
  __shared__ float rnorm_s[8];
  __shared__ float smax_s[8];
  __shared__ float rsum_s[8];

  const int tid = threadIdx.x;
  const int bid = blockIdx.x;
  const int n   = bid / 150;
  const int rem = (bid - n*150) * 8;
  const float* __restrict__ xb = x + (size_t)n*C_*HW_ + rem;

  const int pix = tid & 7;
  const int q   = tid >> 3;

  {
    const int c  = tid >> 1;
    const int p0 = (tid & 1) << 2;
    const float4 v = *(const float4*)(xb + (size_t)c*HW_ + p0);
    xs[p0+0][c] = v.x; xs[p0+1][c] = v.y;
    xs[p0+2][c] = v.z; xs[p0+3][c] = v.w;
  }
  __syncthreads();

  {
    const float4 v = *(const float4*)&xs[pix][q*4];
    red[pix][q] = (v.x*v.x + v.y*v.y) + (v.z*v.z + v.w*v.w);
  }
  __syncthreads();
  if (tid < 64) {
    const int p = tid >> 3, j = tid & 7;
    float s = ((red[p][j] + red[p][j+8]) + (red[p][j+16] + red[p][j+24]));
    s += __shfl_xor(s, 1, 64); s += __shfl_xor(s, 2, 64); s += __shfl_xor(s, 4, 64);
    if (j == 0) rnorm_s[p] = 1.f / fmaxf(sqrtf(s), 1e-12f);
  }
  __syncthreads();

  {
    const float* __restrict__ w0 = cw + (q*2)*C_;
    const float* __restrict__ w1 = w0 + C_;
    float a0 = 0.f, a1 = 0.f;
    #pragma unroll 8
    for (int c0 = 0; c0 < C_; c0 += 4) {
      const float4 xv = *(const float4*)&xs[pix][c0];
      const float4 wa = *(const float4*)(w0 + c0);
      const float4 wb = *(const float4*)(w1 + c0);
      a0 = fmaf(wa.x, xv.x, a0); a0 = fmaf(wa.y, xv.y, a0);
      a0 = fmaf(wa.z, xv.z, a0); a0 = fmaf(wa.w, xv.w, a0);
      a1 = fmaf(wb.x, xv.x, a1); a1 = fmaf(wb.y, xv.y, a1);
      a1 = fmaf(wb.z, xv.z, a1); a1 = fmaf(wb.w, xv.w, a1);
    }
    const float rn = rnorm_s[pix];
    float2 lv; lv.x = a0 * rn; lv.y = a1 * rn;
    *(float2*)&ls[pix][q*2] = lv;
  }

  {
    const int c  = tid >> 1;
    const int p0 = (tid & 1) << 2;
    float4 o;
    o.x = xs[p0+0][c] * rnorm_s[p0+0];
    o.y = xs[p0+1][c] * rnorm_s[p0+1];
    o.z = xs[p0+2][c] * rnorm_s[p0+2];
    o.w = xs[p0+3][c] * rnorm_s[p0+3];
    *(float4*)(xn + ((size_t)n*C_ + c)*HW_ + rem + p0) = o;
  }
  __syncthreads();

  if (tid < 64) {
    const int p = tid >> 3, j = tid & 7;
    const float4 v0 = *(const float4*)&ls[p][j*8];
    const float4 v1 = *(const float4*)&ls[p][j*8 + 4];
    float m = fmaxf(fmaxf(fmaxf(v0.x, v0.y), fmaxf(v0.z, v0.w)),
                    fmaxf(fmaxf(v1.x, v1.y), fmaxf(v1.z, v1.w)));
    m = fmaxf(m, __shfl_xor(m, 1, 64));
    m = fmaxf(m, __shfl_xor(m, 2, 64));
    m = fmaxf(m, __shfl_xor(m, 4, 64));
    if (j == 0) smax_s[p] = m;
  }
  __syncthreads();

  {
    const float m = smax_s[pix];
    const float2 lv = *(const float2*)&ls[pix][q*2];
    const float e0 = expf(lv.x - m);
    const float e1 = expf(lv.y - m);
    float2 ev; ev.x = e0; ev.y = e1;
    *(float2*)&ls[pix][q*2] = ev;
    red[pix][q] = e0 + e1;
  }
  __syncthreads();
  if (tid < 64) {
    const int p = tid >> 3, j = tid & 7;
    float s = ((red[p][j] + red[p][j+8]) + (red[p][j+16] + red[p][j+24]));
    s += __shfl_xor(s, 1, 64); s += __shfl_xor(s, 2, 64); s += __shfl_xor(s, 4, 64);
    if (j == 0) rsum_s[p] = 1.f / s;
  }
  __syncthreads();

  {
    const int k  = tid >> 2;
    const int ph = (tid & 3) << 1;
    float2 o;
    o.x = ls[ph + 0][k] * rsum_s[ph + 0];
    o.y = ls[ph + 1][k] * rsum_s[ph + 1];
    *(float2*)(sa + ((size_t)n*K_ + k)*HW_ + rem + ph) = o;
  }
}

// ---------------------------------------------------------------------------
// K2 v4: k-tiled x4. Thread = (c, w, half) holds xv[22] in regs, loops over
// 4 k's (sv wave-shared/L1-broadcast). xn L2/L3 re-reads 64x -> 16x.
// Grid (16 cgroups, 16 kgroups, 8 n-halves) = 2048 blocks.
// ---------------------------------------------------------------------------
__global__ __launch_bounds__(256, 6) void k2_box(
    const float* __restrict__ xn, const float* __restrict__ sa,
    const float* __restrict__ cent, float* __restrict__ out)
{
  const int tid = threadIdx.x;
  const int w   = tid & 31;
  const int wc  = (w < W_) ? w : (W_ - 1);   // clamp pad lanes 30,31
  const int c   = (blockIdx.x << 3) + (tid >> 5);
  const int kg  = blockIdx.y;                // k = kg*4 .. kg*4+3
  const int nh  = blockIdx.z;
  const int n   = nh >> 1;
  const int r0  = (nh & 1) * 18;

  const float* __restrict__ xp = xn + (size_t)(n*C_ + c)*HW_ + (size_t)r0*W_ + wc;

  float xv[22];
  #pragma unroll
  for (int h = 0; h < 22; ++h) xv[h] = xp[h*W_];

  #pragma unroll 1
  for (int kk = 0; kk < 4; ++kk) {
    const int k = (kg << 2) + kk;
    const float cv = cent[k*C_ + c];
    const float* __restrict__ sp = sa + (size_t)(n*K_ + k)*HW_ + (size_t)r0*W_ + wc;

    float q[22];
    #pragma unroll
    for (int h = 0; h < 22; ++h) {
      q[h] = (xv[h] - cv) * sp[h*W_];
    }

    float vq = q[0] + q[1] + q[2] + q[3] + q[4];
    float* __restrict__ op = out + (size_t)((n*K_ + k)*C_ + c)*OHW_
                                 + (size_t)r0*OW_ + w;

    #pragma unroll
    for (int i = 0; i < 18; ++i) {
      const float sw = swz_x16(vq);
      float hs = vq;
      hs += dpp0f<0x101>(vq) + dpp0f<0x11F>(sw);
      hs += dpp0f<0x102>(vq) + dpp0f<0x11E>(sw);
      hs += dpp0f<0x103>(vq) + dpp0f<0x11D>(sw);
      hs += dpp0f<0x104>(vq) + dpp0f<0x11C>(sw);
      if (w < OW_) op[i*OW_] = hs * (1.f / (P_*P_));
      if (i < 17) vq += q[i + P_] - q[i];
    }
  }
}

extern "C" void kernel_launch(void* const* d_in, const int* in_sizes, int n_in,
                              void* d_out, int out_size, void* d_ws, size_t ws_size,
                              hipStream_t stream) {
  const float* x  = (const float*)d_in[0];
  const float* cw = (const float*)d_in[1];  // [K,C]
  const float* ce = (const float*)d_in[2];  // [K,C]

  float* xn = (float*)d_ws;                 // 4*128*1200 f32
  float* sa = xn + (size_t)N_*C_*HW_;       // 4*64*1200 f32
  float* out = (float*)d_out;

  k1_fused<<<dim3(600), dim3(256), 0, stream>>>(x, cw, xn, sa);
  k2_box  <<<dim3(16, 16, N_*2), dim3(256), 0, stream>>>(xn, sa, ce, out);
}